// Round 5
// baseline (573.554 us; speedup 1.0000x reference)
//
#include <hip/hip_runtime.h>
#include <math.h>

#define BATCH 32
#define SEQ   4096
#define DM    256
#define NS    64

// z-space recurrence: z = a*z + u, x = B_tilde * z exactly.
// y = sum_n (C*B_tilde)[n] * z[n].
// chain = one (b,d) recurrence. 4 lanes per chain, 16 states per lane.
// wave = 64 lanes = 16 chains = (one b, 16 consecutive d).
// u broadcast: all 4 lanes of a chain load the SAME u address (dup-address
// global loads coalesce to one request) -- no ds_bpermute in the loop.
// Live set = a[16]+cbt[16]+z[16] = 48 floats + ~12 overhead: fits the
// 64-VGPR occupancy tier (8 waves/SIMD) with NO spill. Rounds 2-4 proved
// the 96-float 32-state layout always gets its invariants parked in
// AGPR/scratch (VGPR clamped to 64, +60..120MB scratch WRITE, VALUBusy<=49%)
// regardless of launch_bounds / waves_per_eu flags.

// Pass 1: local z-scan from zero per chunk; store end z-state into S[g].
// Launched for chunks 0..C-2 only (last chunk's local state is unused).
__global__ __launch_bounds__(256, 2)
void pass1_kernel(const float* __restrict__ u,
                  const float* __restrict__ log_dt,
                  const float* __restrict__ A_real,
                  float* __restrict__ S, int Tc) {
    int wave = (blockIdx.x * blockDim.x + threadIdx.x) >> 6;
    int lane = threadIdx.x & 63;
    int w  = wave & 511;   // chain group within chunk
    int g  = wave >> 9;    // chunk
    int b  = w >> 4;
    int d0 = (w & 15) << 4;
    int c   = lane >> 2;   // chain within wave (0..15)
    int sub = lane & 3;    // quarter of the state vector
    int d   = d0 + c;
    int n0  = sub << 4;

    float a[16], z[16];
    {
        float dt = expf(log_dt[d]);  // DT_SCALE = 1.0
        const float* Ap = A_real + d * NS + n0;
#pragma unroll
        for (int k = 0; k < 16; ++k) {
            a[k] = expf(Ap[k] * dt);
            z[k] = 0.0f;
        }
    }

    // all 4 sub-lanes of chain c load the same address (free dup broadcast)
    const float* uptr = u + (size_t)b * SEQ * DM + (size_t)(g * Tc) * DM + d;

    float ucur = *uptr;
    for (int t = 0; t < Tc - 1; ++t) {
        float unext = uptr[DM];   // 1-step prefetch
        uptr += DM;
#pragma unroll
        for (int k = 0; k < 16; ++k)
            z[k] = fmaf(a[k], z[k], ucur);
        ucur = unext;
    }
#pragma unroll
    for (int k = 0; k < 16; ++k)
        z[k] = fmaf(a[k], z[k], ucur);

    float* Sp = S + (((size_t)g * BATCH + b) * DM + d) * NS + n0;
    float4* Sp4 = (float4*)Sp;
#pragma unroll
    for (int j = 0; j < 4; ++j)
        Sp4[j] = make_float4(z[4 * j], z[4 * j + 1], z[4 * j + 2], z[4 * j + 3]);
}

// Pass 2: sequential chunk combine in z-space, in place. After this, S[g]
// holds the true initial z-state for chunk g (z0[0] = x0 / B_tilde, guarded).
__global__ void pass2_kernel(float* __restrict__ S,
                             const float* __restrict__ log_dt,
                             const float* __restrict__ A_real,
                             const float* __restrict__ B,
                             const float* __restrict__ x0,
                             int C, int Tc) {
    int idx = blockIdx.x * blockDim.x + threadIdx.x;  // b*16384 + d*64 + n
    if (idx >= BATCH * DM * NS) return;
    int dn = idx & (DM * NS - 1);
    int d = dn >> 6;
    float ar = A_real[dn];
    float dt = expf(log_dt[d]);
    float aT = expf(ar * dt * (float)Tc);  // a^Tc
    float x0v = x0[dn];
    float prev;
    if (x0v == 0.0f) {
        prev = 0.0f;                       // common/bench case
    } else {
        float at = expf(ar * dt);
        float bt = (1.0f - at) * B[dn] / ar;
        prev = (bt != 0.0f) ? (x0v / bt) : 0.0f;
    }
    for (int g = 0; g < C - 1; ++g) {
        float* p = S + (size_t)g * (BATCH * DM * NS) + idx;
        float s = *p;
        *p = prev;
        prev = fmaf(aT, prev, s);
    }
    // last chunk: only needs its initial state (no local end-state stored)
    S[(size_t)(C - 1) * (BATCH * DM * NS) + idx] = prev;
}

// Pass 3: full z-scan per chunk from S[g], emit y = dot(cbt, z) every step.
__global__ __launch_bounds__(256, 2)
void pass3_kernel(const float* __restrict__ u,
                  const float* __restrict__ log_dt,
                  const float* __restrict__ A_real,
                  const float* __restrict__ B,
                  const float* __restrict__ Cm,
                  const float* __restrict__ S,
                  const float* __restrict__ x0,
                  float* __restrict__ y, int Tc, int useS) {
    int wave = (blockIdx.x * blockDim.x + threadIdx.x) >> 6;
    int lane = threadIdx.x & 63;
    int w  = wave & 511;
    int g  = wave >> 9;
    int b  = w >> 4;
    int d0 = (w & 15) << 4;
    int c   = lane >> 2;
    int sub = lane & 3;
    int d   = d0 + c;
    int n0  = sub << 4;

    float a[16], cbt[16], z[16];
    {
        float dt = expf(log_dt[d]);
        const float* Ap = A_real + d * NS + n0;
        const float* Bp = B + d * NS + n0;
        const float* Cp = Cm + d * NS + n0;
#pragma unroll
        for (int k = 0; k < 16; ++k) {
            float ar = Ap[k];
            float at = expf(ar * dt);
            a[k] = at;
            cbt[k] = Cp[k] * ((1.0f - at) * Bp[k] / ar);  // C * B_tilde
        }
        if (useS) {
            const float4* Sp4 = (const float4*)(S +
                (((size_t)g * BATCH + b) * DM + d) * NS + n0);
#pragma unroll
            for (int j = 0; j < 4; ++j) {
                float4 v = Sp4[j];
                z[4 * j] = v.x; z[4 * j + 1] = v.y;
                z[4 * j + 2] = v.z; z[4 * j + 3] = v.w;
            }
        } else {
            const float* Xp = x0 + d * NS + n0;
#pragma unroll
            for (int k = 0; k < 16; ++k) {
                float x0v = Xp[k];
                if (x0v == 0.0f) { z[k] = 0.0f; }
                else {
                    float bt = (1.0f - a[k]) * Bp[k] / Ap[k];
                    z[k] = (bt != 0.0f) ? (x0v / bt) : 0.0f;
                }
            }
        }
    }

    const float* uptr = u + (size_t)b * SEQ * DM + (size_t)(g * Tc) * DM + d;
    float* yptr = y + (size_t)b * SEQ * DM + (size_t)(g * Tc) * DM + d;

    float ucur = *uptr;
    for (int t = 0; t < Tc - 1; ++t) {
        float unext = uptr[DM];   // 1-step prefetch
        uptr += DM;
        float p0 = 0.0f, p1 = 0.0f;
#pragma unroll
        for (int k = 0; k < 16; k += 2) {
            z[k]     = fmaf(a[k],     z[k],     ucur); p0 = fmaf(cbt[k],     z[k],     p0);
            z[k + 1] = fmaf(a[k + 1], z[k + 1], ucur); p1 = fmaf(cbt[k + 1], z[k + 1], p1);
        }
        float p = p0 + p1;
        p += __shfl_xor(p, 1);    // combine the four quarter-state partials
        p += __shfl_xor(p, 2);
        if (sub == 0) *yptr = p;
        yptr += DM;
        ucur = unext;
    }
    {   // final step
        float p0 = 0.0f, p1 = 0.0f;
#pragma unroll
        for (int k = 0; k < 16; k += 2) {
            z[k]     = fmaf(a[k],     z[k],     ucur); p0 = fmaf(cbt[k],     z[k],     p0);
            z[k + 1] = fmaf(a[k + 1], z[k + 1], ucur); p1 = fmaf(cbt[k + 1], z[k + 1], p1);
        }
        float p = p0 + p1;
        p += __shfl_xor(p, 1);
        p += __shfl_xor(p, 2);
        if (sub == 0) *yptr = p;
    }
}

extern "C" void kernel_launch(void* const* d_in, const int* in_sizes, int n_in,
                              void* d_out, int out_size, void* d_ws, size_t ws_size,
                              hipStream_t stream) {
    const float* u      = (const float*)d_in[0];
    const float* log_dt = (const float*)d_in[1];
    const float* A_real = (const float*)d_in[2];
    const float* B      = (const float*)d_in[3];
    const float* Cm     = (const float*)d_in[4];
    const float* x0     = (const float*)d_in[5];
    float* y = (float*)d_out;
    float* S = (float*)d_ws;

    const size_t per_chunk = (size_t)BATCH * DM * NS * sizeof(float);  // 2 MB
    int C = 16;  // 8192 waves in pass3 -> 8 waves/SIMD at the 64-VGPR tier
    while (C > 1 && (size_t)C * per_chunk > ws_size) C >>= 1;
    if ((size_t)C * per_chunk > ws_size) C = 1;
    int Tc = SEQ / C;

    if (C > 1) {
        // chunks 0..C-2 need local end-states; 512 waves/chunk, 4 waves/block
        pass1_kernel<<<dim3((C - 1) * 128), dim3(256), 0, stream>>>(
            u, log_dt, A_real, S, Tc);
        pass2_kernel<<<dim3((BATCH * DM * NS) / 256), dim3(256), 0, stream>>>(
            S, log_dt, A_real, B, x0, C, Tc);
    }
    pass3_kernel<<<dim3(C * 128), dim3(256), 0, stream>>>(
        u, log_dt, A_real, B, Cm, S, x0, y, Tc, (C > 1) ? 1 : 0);
}

// Round 6
// 410.579 us; speedup vs baseline: 1.3969x; 1.3969x over previous
//
#include <hip/hip_runtime.h>
#include <math.h>

#define BATCH 32
#define SEQ   4096
#define DM    256
#define NS    64

// z-space recurrence: z = a*z + u, x = B_tilde * z exactly.
// y = sum_n (C*B_tilde)[n] * z[n].
// chain = one (b,d) recurrence. 4 lanes per chain, 16 states per lane.
// wave = 64 lanes = 16 chains = (one b, 16 consecutive d).
// u broadcast: all 4 lanes of a chain load the SAME u address (coalesces
// to one 64B request per wave-step) -- no ds_bpermute in the loop.
// Live set = a[16]+cbt[16]+z[16] = 48 floats (+8 prefetch regs): fits the
// 64-VGPR tier with NO spill (r5 verified: VGPR=56, WRITE==output size).
// Round-5 bottleneck was latency exposure (1-step prefetch = ~80 cycles of
// cover per load). This round: 4-deep batched prefetch, both passes.

// Pass 1: local z-scan from zero per chunk; store end z-state into S[g].
// Launched for chunks 0..C-2 only (last chunk's local state is unused).
__global__ __launch_bounds__(256, 2)
void pass1_kernel(const float* __restrict__ u,
                  const float* __restrict__ log_dt,
                  const float* __restrict__ A_real,
                  float* __restrict__ S, int Tc) {
    int wave = (blockIdx.x * blockDim.x + threadIdx.x) >> 6;
    int lane = threadIdx.x & 63;
    int w  = wave & 511;   // chain group within chunk
    int g  = wave >> 9;    // chunk
    int b  = w >> 4;
    int d0 = (w & 15) << 4;
    int c   = lane >> 2;   // chain within wave (0..15)
    int sub = lane & 3;    // quarter of the state vector
    int d   = d0 + c;
    int n0  = sub << 4;

    float a[16], z[16];
    {
        float dt = expf(log_dt[d]);  // DT_SCALE = 1.0
        const float* Ap = A_real + d * NS + n0;
#pragma unroll
        for (int k = 0; k < 16; ++k) {
            a[k] = expf(Ap[k] * dt);
            z[k] = 0.0f;
        }
    }

    const float* uptr = u + (size_t)b * SEQ * DM + (size_t)(g * Tc) * DM + d;

#define P1STEP(UV)                                   \
    {                                                \
        _Pragma("unroll")                            \
        for (int k = 0; k < 16; ++k)                 \
            z[k] = fmaf(a[k], z[k], (UV));           \
    }

    float uc0 = uptr[0], uc1 = uptr[DM], uc2 = uptr[2 * DM], uc3 = uptr[3 * DM];
    for (int t4 = 0; t4 < Tc - 4; t4 += 4) {
        uptr += 4 * DM;
        float uf0 = uptr[0], uf1 = uptr[DM], uf2 = uptr[2 * DM], uf3 = uptr[3 * DM];
        P1STEP(uc0) P1STEP(uc1) P1STEP(uc2) P1STEP(uc3)
        uc0 = uf0; uc1 = uf1; uc2 = uf2; uc3 = uf3;
    }
    P1STEP(uc0) P1STEP(uc1) P1STEP(uc2) P1STEP(uc3)
#undef P1STEP

    float* Sp = S + (((size_t)g * BATCH + b) * DM + d) * NS + n0;
    float4* Sp4 = (float4*)Sp;
#pragma unroll
    for (int j = 0; j < 4; ++j)
        Sp4[j] = make_float4(z[4 * j], z[4 * j + 1], z[4 * j + 2], z[4 * j + 3]);
}

// Pass 2: sequential chunk combine in z-space, in place. After this, S[g]
// holds the true initial z-state for chunk g (z0[0] = x0 / B_tilde, guarded).
__global__ void pass2_kernel(float* __restrict__ S,
                             const float* __restrict__ log_dt,
                             const float* __restrict__ A_real,
                             const float* __restrict__ B,
                             const float* __restrict__ x0,
                             int C, int Tc) {
    int idx = blockIdx.x * blockDim.x + threadIdx.x;  // b*16384 + d*64 + n
    if (idx >= BATCH * DM * NS) return;
    int dn = idx & (DM * NS - 1);
    int d = dn >> 6;
    float ar = A_real[dn];
    float dt = expf(log_dt[d]);
    float aT = expf(ar * dt * (float)Tc);  // a^Tc
    float x0v = x0[dn];
    float prev;
    if (x0v == 0.0f) {
        prev = 0.0f;                       // common/bench case
    } else {
        float at = expf(ar * dt);
        float bt = (1.0f - at) * B[dn] / ar;
        prev = (bt != 0.0f) ? (x0v / bt) : 0.0f;
    }
    for (int g = 0; g < C - 1; ++g) {
        float* p = S + (size_t)g * (BATCH * DM * NS) + idx;
        float s = *p;
        *p = prev;
        prev = fmaf(aT, prev, s);
    }
    // last chunk: only needs its initial state (no local end-state stored)
    S[(size_t)(C - 1) * (BATCH * DM * NS) + idx] = prev;
}

// Pass 3: full z-scan per chunk from S[g], emit y = dot(cbt, z) every step.
__global__ __launch_bounds__(256, 2)
void pass3_kernel(const float* __restrict__ u,
                  const float* __restrict__ log_dt,
                  const float* __restrict__ A_real,
                  const float* __restrict__ B,
                  const float* __restrict__ Cm,
                  const float* __restrict__ S,
                  const float* __restrict__ x0,
                  float* __restrict__ y, int Tc, int useS) {
    int wave = (blockIdx.x * blockDim.x + threadIdx.x) >> 6;
    int lane = threadIdx.x & 63;
    int w  = wave & 511;
    int g  = wave >> 9;
    int b  = w >> 4;
    int d0 = (w & 15) << 4;
    int c   = lane >> 2;
    int sub = lane & 3;
    int d   = d0 + c;
    int n0  = sub << 4;

    float a[16], cbt[16], z[16];
    {
        float dt = expf(log_dt[d]);
        const float* Ap = A_real + d * NS + n0;
        const float* Bp = B + d * NS + n0;
        const float* Cp = Cm + d * NS + n0;
#pragma unroll
        for (int k = 0; k < 16; ++k) {
            float ar = Ap[k];
            float at = expf(ar * dt);
            a[k] = at;
            cbt[k] = Cp[k] * ((1.0f - at) * Bp[k] / ar);  // C * B_tilde
        }
        if (useS) {
            const float4* Sp4 = (const float4*)(S +
                (((size_t)g * BATCH + b) * DM + d) * NS + n0);
#pragma unroll
            for (int j = 0; j < 4; ++j) {
                float4 v = Sp4[j];
                z[4 * j] = v.x; z[4 * j + 1] = v.y;
                z[4 * j + 2] = v.z; z[4 * j + 3] = v.w;
            }
        } else {
            const float* Xp = x0 + d * NS + n0;
#pragma unroll
            for (int k = 0; k < 16; ++k) {
                float x0v = Xp[k];
                if (x0v == 0.0f) { z[k] = 0.0f; }
                else {
                    float bt = (1.0f - a[k]) * Bp[k] / Ap[k];
                    z[k] = (bt != 0.0f) ? (x0v / bt) : 0.0f;
                }
            }
        }
    }

    const float* uptr = u + (size_t)b * SEQ * DM + (size_t)(g * Tc) * DM + d;
    float* yptr = y + (size_t)b * SEQ * DM + (size_t)(g * Tc) * DM + d;

#define P3STEP(UV)                                                            \
    {                                                                         \
        float p0 = 0.0f, p1 = 0.0f;                                           \
        _Pragma("unroll")                                                     \
        for (int k = 0; k < 16; k += 2) {                                     \
            z[k]   = fmaf(a[k],   z[k],   (UV)); p0 = fmaf(cbt[k],   z[k],   p0); \
            z[k+1] = fmaf(a[k+1], z[k+1], (UV)); p1 = fmaf(cbt[k+1], z[k+1], p1); \
        }                                                                     \
        float p = p0 + p1;                                                    \
        p += __shfl_xor(p, 1);                                                \
        p += __shfl_xor(p, 2);                                                \
        if (sub == 0) *yptr = p;                                              \
        yptr += DM;                                                           \
    }

    float uc0 = uptr[0], uc1 = uptr[DM], uc2 = uptr[2 * DM], uc3 = uptr[3 * DM];
    for (int t4 = 0; t4 < Tc - 4; t4 += 4) {
        uptr += 4 * DM;
        float uf0 = uptr[0], uf1 = uptr[DM], uf2 = uptr[2 * DM], uf3 = uptr[3 * DM];
        P3STEP(uc0) P3STEP(uc1) P3STEP(uc2) P3STEP(uc3)
        uc0 = uf0; uc1 = uf1; uc2 = uf2; uc3 = uf3;
    }
    P3STEP(uc0) P3STEP(uc1) P3STEP(uc2) P3STEP(uc3)
#undef P3STEP
}

extern "C" void kernel_launch(void* const* d_in, const int* in_sizes, int n_in,
                              void* d_out, int out_size, void* d_ws, size_t ws_size,
                              hipStream_t stream) {
    const float* u      = (const float*)d_in[0];
    const float* log_dt = (const float*)d_in[1];
    const float* A_real = (const float*)d_in[2];
    const float* B      = (const float*)d_in[3];
    const float* Cm     = (const float*)d_in[4];
    const float* x0     = (const float*)d_in[5];
    float* y = (float*)d_out;
    float* S = (float*)d_ws;

    const size_t per_chunk = (size_t)BATCH * DM * NS * sizeof(float);  // 2 MB
    int C = 16;  // 8192 waves in pass3 -> 8 waves/SIMD at the 64-VGPR tier
    while (C > 1 && (size_t)C * per_chunk > ws_size) C >>= 1;
    if ((size_t)C * per_chunk > ws_size) C = 1;
    int Tc = SEQ / C;

    if (C > 1) {
        // chunks 0..C-2 need local end-states; 512 waves/chunk, 4 waves/block
        pass1_kernel<<<dim3((C - 1) * 128), dim3(256), 0, stream>>>(
            u, log_dt, A_real, S, Tc);
        pass2_kernel<<<dim3((BATCH * DM * NS) / 256), dim3(256), 0, stream>>>(
            S, log_dt, A_real, B, x0, C, Tc);
    }
    pass3_kernel<<<dim3(C * 128), dim3(256), 0, stream>>>(
        u, log_dt, A_real, B, Cm, S, x0, y, Tc, (C > 1) ? 1 : 0);
}

// Round 7
// 388.422 us; speedup vs baseline: 1.4766x; 1.0570x over previous
//
#include <hip/hip_runtime.h>
#include <math.h>

#define BATCH 32
#define SEQ   4096
#define DM    256
#define NS    64
#define TSTEP 16   // time steps per staged LDS tile

// z-space recurrence: z = a*z + u, x = B_tilde * z exactly.
// y = sum_n (C*B_tilde)[n] * z[n].
// chain = one (b,d) recurrence. 4 lanes per chain, 16 states per lane.
// wave = 64 lanes = 16 chains = (one b, 16 consecutive d).
// u staging: per-wave double-buffered LDS tile [16 t][16 d]. ONE coalesced
// float4 load per lane covers 16 steps (16x fewer VMEM instrs than r6's
// per-step dup loads; load-to-use = a full 16-step compute phase). Per step
// a broadcast ds_read_b32 feeds all 4 sub-lanes of a chain (conflict-free).
// Buffers are PER-WAVE -> no __syncthreads anywhere.
// Live set stays ~60 VGPR (r2-r4 lesson: >64 live floats => scratch parking).

// Pass 1: local z-scan from zero per chunk; store end z-state into S[g].
// Launched for chunks 0..C-2 only (last chunk's local state is unused).
__global__ __launch_bounds__(256, 2)
void pass1_kernel(const float* __restrict__ u,
                  const float* __restrict__ log_dt,
                  const float* __restrict__ A_real,
                  float* __restrict__ S, int Tc) {
    __shared__ float tiles[4][2][TSTEP][16];  // 8 KB: 4 waves x dbuf x tile
    int wid  = threadIdx.x >> 6;
    int lane = threadIdx.x & 63;
    int wave = (blockIdx.x * blockDim.x + threadIdx.x) >> 6;
    int w  = wave & 511;   // chain group within chunk
    int g  = wave >> 9;    // chunk
    int b  = w >> 4;
    int d0 = (w & 15) << 4;
    int c   = lane >> 2;   // chain within wave (0..15)
    int sub = lane & 3;    // quarter of the state vector
    int d   = d0 + c;
    int n0  = sub << 4;

    float a[16], z[16];
    {
        float dt = expf(log_dt[d]);  // DT_SCALE = 1.0
        const float* Ap = A_real + d * NS + n0;
#pragma unroll
        for (int k = 0; k < 16; ++k) {
            a[k] = expf(Ap[k] * dt);
            z[k] = 0.0f;
        }
    }

    // staging: lane L loads u[t0 + (L>>2)][d0 + (L&3)*4 .. +3] (float4)
    const float* gsrc = u + (size_t)b * SEQ * DM + (size_t)(g * Tc) * DM
                        + (size_t)(lane >> 2) * DM + d0 + ((lane & 3) << 2);
    const size_t tadv = (size_t)TSTEP * DM;
    float* slot0 = &tiles[wid][0][0][0] + (lane << 2);  // lane's 16B in buf0
    const int ntiles = Tc / TSTEP;

    // prologue: tile 0 -> buf0; tile 1 in regs
    float4 rnext = *(const float4*)gsrc;
    *(float4*)slot0 = rnext;
    gsrc += tadv;
    rnext = *(const float4*)gsrc;
    gsrc += tadv;

    for (int tile = 0; tile < ntiles; ++tile) {
        int cur = tile & 1;
        if (tile + 1 < ntiles)
            *(float4*)(slot0 + (((tile + 1) & 1) << 8)) = rnext;  // stage next
        if (tile + 2 < ntiles) {
            rnext = *(const float4*)gsrc;   // issue load 2 tiles ahead
            gsrc += tadv;
        }
        const float* tb = &tiles[wid][cur][0][0] + c;
#pragma unroll
        for (int s = 0; s < TSTEP; ++s) {
            float uv = tb[s << 4];          // broadcast ds_read_b32
#pragma unroll
            for (int k = 0; k < 16; ++k)
                z[k] = fmaf(a[k], z[k], uv);
        }
    }

    float* Sp = S + (((size_t)g * BATCH + b) * DM + d) * NS + n0;
    float4* Sp4 = (float4*)Sp;
#pragma unroll
    for (int j = 0; j < 4; ++j)
        Sp4[j] = make_float4(z[4 * j], z[4 * j + 1], z[4 * j + 2], z[4 * j + 3]);
}

// Pass 2: sequential chunk combine in z-space, in place. After this, S[g]
// holds the true initial z-state for chunk g (z0[0] = x0 / B_tilde, guarded).
// Gather-then-scan: all C loads issued independently up front (round 6's
// version serialized 16 dependent global round trips).
__global__ void pass2_kernel(float* __restrict__ S,
                             const float* __restrict__ log_dt,
                             const float* __restrict__ A_real,
                             const float* __restrict__ B,
                             const float* __restrict__ x0,
                             int C, int Tc) {
    int idx = blockIdx.x * blockDim.x + threadIdx.x;  // b*16384 + d*64 + n
    if (idx >= BATCH * DM * NS) return;
    int dn = idx & (DM * NS - 1);
    int d = dn >> 6;
    float ar = A_real[dn];
    float dt = expf(log_dt[d]);
    float aT = expf(ar * dt * (float)Tc);  // a^Tc
    float x0v = x0[dn];
    float prev;
    if (x0v == 0.0f) {
        prev = 0.0f;                       // common/bench case
    } else {
        float at = expf(ar * dt);
        float bt = (1.0f - at) * B[dn] / ar;
        prev = (bt != 0.0f) ? (x0v / bt) : 0.0f;
    }
    const size_t stride = (size_t)BATCH * DM * NS;
    if (C == 16) {
        float v[15];
#pragma unroll
        for (int g = 0; g < 15; ++g) v[g] = S[(size_t)g * stride + idx];
#pragma unroll
        for (int g = 0; g < 15; ++g) {
            S[(size_t)g * stride + idx] = prev;
            prev = fmaf(aT, prev, v[g]);
        }
        S[15 * stride + idx] = prev;
    } else {
        for (int g = 0; g < C - 1; ++g) {
            float* p = S + (size_t)g * stride + idx;
            float s = *p;
            *p = prev;
            prev = fmaf(aT, prev, s);
        }
        S[(size_t)(C - 1) * stride + idx] = prev;
    }
}

// Pass 3: full z-scan per chunk from S[g], emit y = dot(cbt, z) every step.
__global__ __launch_bounds__(256, 2)
void pass3_kernel(const float* __restrict__ u,
                  const float* __restrict__ log_dt,
                  const float* __restrict__ A_real,
                  const float* __restrict__ B,
                  const float* __restrict__ Cm,
                  const float* __restrict__ S,
                  const float* __restrict__ x0,
                  float* __restrict__ y, int Tc, int useS) {
    __shared__ float tiles[4][2][TSTEP][16];
    int wid  = threadIdx.x >> 6;
    int lane = threadIdx.x & 63;
    int wave = (blockIdx.x * blockDim.x + threadIdx.x) >> 6;
    int w  = wave & 511;
    int g  = wave >> 9;
    int b  = w >> 4;
    int d0 = (w & 15) << 4;
    int c   = lane >> 2;
    int sub = lane & 3;
    int d   = d0 + c;
    int n0  = sub << 4;

    float a[16], cbt[16], z[16];
    {
        float dt = expf(log_dt[d]);
        const float* Ap = A_real + d * NS + n0;
        const float* Bp = B + d * NS + n0;
        const float* Cp = Cm + d * NS + n0;
#pragma unroll
        for (int k = 0; k < 16; ++k) {
            float ar = Ap[k];
            float at = expf(ar * dt);
            a[k] = at;
            cbt[k] = Cp[k] * ((1.0f - at) * Bp[k] / ar);  // C * B_tilde
        }
        if (useS) {
            const float4* Sp4 = (const float4*)(S +
                (((size_t)g * BATCH + b) * DM + d) * NS + n0);
#pragma unroll
            for (int j = 0; j < 4; ++j) {
                float4 v = Sp4[j];
                z[4 * j] = v.x; z[4 * j + 1] = v.y;
                z[4 * j + 2] = v.z; z[4 * j + 3] = v.w;
            }
        } else {
            const float* Xp = x0 + d * NS + n0;
#pragma unroll
            for (int k = 0; k < 16; ++k) {
                float x0v = Xp[k];
                if (x0v == 0.0f) { z[k] = 0.0f; }
                else {
                    float bt = (1.0f - a[k]) * Bp[k] / Ap[k];
                    z[k] = (bt != 0.0f) ? (x0v / bt) : 0.0f;
                }
            }
        }
    }

    const float* gsrc = u + (size_t)b * SEQ * DM + (size_t)(g * Tc) * DM
                        + (size_t)(lane >> 2) * DM + d0 + ((lane & 3) << 2);
    const size_t tadv = (size_t)TSTEP * DM;
    float* slot0 = &tiles[wid][0][0][0] + (lane << 2);
    const int ntiles = Tc / TSTEP;
    float* yptr = y + (size_t)b * SEQ * DM + (size_t)(g * Tc) * DM + d;

    float4 rnext = *(const float4*)gsrc;
    *(float4*)slot0 = rnext;
    gsrc += tadv;
    rnext = *(const float4*)gsrc;
    gsrc += tadv;

    for (int tile = 0; tile < ntiles; ++tile) {
        int cur = tile & 1;
        if (tile + 1 < ntiles)
            *(float4*)(slot0 + (((tile + 1) & 1) << 8)) = rnext;
        if (tile + 2 < ntiles) {
            rnext = *(const float4*)gsrc;
            gsrc += tadv;
        }
        const float* tb = &tiles[wid][cur][0][0] + c;
#pragma unroll
        for (int s = 0; s < TSTEP; ++s) {
            float uv = tb[s << 4];          // broadcast ds_read_b32
            float p0 = 0.0f, p1 = 0.0f;
#pragma unroll
            for (int k = 0; k < 16; k += 2) {
                z[k]     = fmaf(a[k],     z[k],     uv); p0 = fmaf(cbt[k],     z[k],     p0);
                z[k + 1] = fmaf(a[k + 1], z[k + 1], uv); p1 = fmaf(cbt[k + 1], z[k + 1], p1);
            }
            float p = p0 + p1;
            p += __shfl_xor(p, 1);   // combine the four quarter-state partials
            p += __shfl_xor(p, 2);
            if (sub == 0) *yptr = p; // 16 consecutive d -> 64B/wave store
            yptr += DM;
        }
    }
}

extern "C" void kernel_launch(void* const* d_in, const int* in_sizes, int n_in,
                              void* d_out, int out_size, void* d_ws, size_t ws_size,
                              hipStream_t stream) {
    const float* u      = (const float*)d_in[0];
    const float* log_dt = (const float*)d_in[1];
    const float* A_real = (const float*)d_in[2];
    const float* B      = (const float*)d_in[3];
    const float* Cm     = (const float*)d_in[4];
    const float* x0     = (const float*)d_in[5];
    float* y = (float*)d_out;
    float* S = (float*)d_ws;

    const size_t per_chunk = (size_t)BATCH * DM * NS * sizeof(float);  // 2 MB
    int C = 16;  // 8192 waves in pass3; Tc=256 -> 16 tiles/chunk
    while (C > 1 && (size_t)C * per_chunk > ws_size) C >>= 1;
    if ((size_t)C * per_chunk > ws_size) C = 1;
    int Tc = SEQ / C;

    if (C > 1) {
        // chunks 0..C-2 need local end-states; 512 waves/chunk, 4 waves/block
        pass1_kernel<<<dim3((C - 1) * 128), dim3(256), 0, stream>>>(
            u, log_dt, A_real, S, Tc);
        pass2_kernel<<<dim3((BATCH * DM * NS) / 256), dim3(256), 0, stream>>>(
            S, log_dt, A_real, B, x0, C, Tc);
    }
    pass3_kernel<<<dim3(C * 128), dim3(256), 0, stream>>>(
        u, log_dt, A_real, B, Cm, S, x0, y, Tc, (C > 1) ? 1 : 0);
}